// Round 21
// baseline (5165.923 us; speedup 1.0000x reference)
//
#include <hip/hip_runtime.h>

#define F_ACC  1
#define F_ACT  2

__device__ __forceinline__ float lrelu(float x) { return x >= 0.f ? x : 0.2f * x; }

// ---------------------------------------------------------------------------
// Generic fp32 tiled GEMM (trunk only; continuous path, fast fmaf ok)
// ---------------------------------------------------------------------------
template<int BM, int BO, int TM, int TO>
__global__ __launch_bounds__(256) void gemm_k(
    const float* __restrict__ A, int lda,
    const float* __restrict__ W, int ldw,
    float* __restrict__ Out, int ldo,
    int K, int flags,
    const float* __restrict__ s, const float* __restrict__ t)
{
    constexpr int BK = 32;
    __shared__ float As[BK][BM + 4];
    __shared__ float Ws[BK][BO + 4];
    const int tid = threadIdx.x;
    const int bm = blockIdx.x * BM;
    const int bo = blockIdx.y * BO;
    const int tx = tid & 15;
    const int ty = tid >> 4;
    const int sr = tid >> 3;
    const int sc = (tid & 7) << 2;

    float acc[TM][TO];
#pragma unroll
    for (int i = 0; i < TM; ++i)
#pragma unroll
        for (int j = 0; j < TO; ++j) acc[i][j] = 0.f;

    for (int k0 = 0; k0 < K; k0 += BK) {
#pragma unroll
        for (int e = 0; e < BM / 32; ++e) {
            const int r = sr + e * 32;
            const float4 v = *reinterpret_cast<const float4*>(
                &A[(size_t)(bm + r) * lda + k0 + sc]);
            As[sc + 0][r] = v.x; As[sc + 1][r] = v.y;
            As[sc + 2][r] = v.z; As[sc + 3][r] = v.w;
        }
#pragma unroll
        for (int e = 0; e < BO / 32; ++e) {
            const int r = sr + e * 32;
            const float4 v = *reinterpret_cast<const float4*>(
                &W[(size_t)(bo + r) * ldw + k0 + sc]);
            Ws[sc + 0][r] = v.x; Ws[sc + 1][r] = v.y;
            Ws[sc + 2][r] = v.z; Ws[sc + 3][r] = v.w;
        }
        __syncthreads();
#pragma unroll
        for (int k = 0; k < BK; ++k) {
            float af[TM], wf[TO];
#pragma unroll
            for (int g = 0; g < TM / 4; ++g) {
                const float4 v = *reinterpret_cast<const float4*>(&As[k][g * 64 + ty * 4]);
                af[g * 4 + 0] = v.x; af[g * 4 + 1] = v.y;
                af[g * 4 + 2] = v.z; af[g * 4 + 3] = v.w;
            }
#pragma unroll
            for (int g = 0; g < TO / 4; ++g) {
                const float4 v = *reinterpret_cast<const float4*>(&Ws[k][g * 64 + tx * 4]);
                wf[g * 4 + 0] = v.x; wf[g * 4 + 1] = v.y;
                wf[g * 4 + 2] = v.z; wf[g * 4 + 3] = v.w;
            }
#pragma unroll
            for (int i = 0; i < TM; ++i)
#pragma unroll
                for (int j = 0; j < TO; ++j)
                    acc[i][j] = fmaf(af[i], wf[j], acc[i][j]);
        }
        __syncthreads();
    }

#pragma unroll
    for (int i = 0; i < TM; ++i) {
        const int gr = bm + (i >> 2) * 64 + ty * 4 + (i & 3);
#pragma unroll
        for (int g = 0; g < TO / 4; ++g) {
            const int go = bo + g * 64 + tx * 4;
            float4 v;
            v.x = acc[i][g * 4 + 0]; v.y = acc[i][g * 4 + 1];
            v.z = acc[i][g * 4 + 2]; v.w = acc[i][g * 4 + 3];
            float* op = &Out[(size_t)gr * ldo + go];
            if (flags & F_ACC) {
                const float4 p = *reinterpret_cast<const float4*>(op);
                v.x += p.x; v.y += p.y; v.z += p.z; v.w += p.w;
            }
            if (flags & F_ACT) {
                v.x = lrelu(v.x * s[go + 0] + t[go + 0]);
                v.y = lrelu(v.y * s[go + 1] + t[go + 1]);
                v.z = lrelu(v.z * s[go + 2] + t[go + 2]);
                v.w = lrelu(v.w * s[go + 3] + t[go + 3]);
            }
            *reinterpret_cast<float4*>(op) = v;
        }
    }
}

// sq L1 from x [B,6,2048]: ascending non-FMA on rounded squares (np.sum n<8).
__global__ __launch_bounds__(256) void sq6x_k(const float* __restrict__ x,
                                              float* __restrict__ sq)
{
    const int i = blockIdx.x * 256 + threadIdx.x;
    const int b = i >> 11, n = i & 2047;
    const float* p = x + (size_t)b * 6 * 2048 + n;
    float s = 0.f;
#pragma unroll
    for (int c = 0; c < 6; ++c) {
        const float v = p[(size_t)c * 2048];
        s = __fadd_rn(s, __fmul_rn(v, v));
    }
    sq[i] = s;
}

// sq C in {64,128}: np pairwise 8-accumulator + tree on rounded squares.
template<int C>
__global__ __launch_bounds__(256) void sqnp_k(const float* __restrict__ F,
                                              int ldf, float* __restrict__ sq)
{
    const int i = blockIdx.x * 256 + threadIdx.x;
    const float* r = F + (size_t)i * ldf;
    float rr[8];
#pragma unroll
    for (int j = 0; j < 8; ++j) rr[j] = __fmul_rn(r[j], r[j]);
    for (int c = 8; c < C; c += 8)
#pragma unroll
        for (int j = 0; j < 8; ++j)
            rr[j] = __fadd_rn(rr[j], __fmul_rn(r[c + j], r[c + j]));
    sq[i] = __fadd_rn(
        __fadd_rn(__fadd_rn(rr[0], rr[1]), __fadd_rn(rr[2], rr[3])),
        __fadd_rn(__fadd_rn(rr[4], rr[5]), __fadd_rn(rr[6], rr[7])));
}

// Distance: G = single ascending-k FMA f32 chain (BLAS sgemm world).
// d = fl(fl(2G - sq_n) - sq_m).  DIRECTX: raw x slice [6,2048].
template<int C, bool DIRECTX>
__global__ __launch_bounds__(256) void distfma_k(
    const float* __restrict__ A, int lda, const float* __restrict__ sq,
    float* __restrict__ D)
{
    __shared__ float As[32][68];
    __shared__ float Bs[32][68];
    const int tid = threadIdx.x;
    const int bm = blockIdx.x * 64;
    const int bo = blockIdx.y * 64;
    const int tx = tid & 15;
    const int ty = tid >> 4;

    float acc[4][4];
#pragma unroll
    for (int i = 0; i < 4; ++i)
#pragma unroll
        for (int j = 0; j < 4; ++j) acc[i][j] = 0.f;

    for (int k0 = 0; k0 < C; k0 += 32) {
#pragma unroll
        for (int e = 0; e < 8; ++e) {
            const int ix = tid + e * 256, r = ix >> 5, c = ix & 31;
            const bool ok = (k0 + c) < C;
            if (DIRECTX) {
                As[c][r] = ok ? A[(size_t)(k0 + c) * 2048 + bm + r] : 0.f;
                Bs[c][r] = ok ? A[(size_t)(k0 + c) * 2048 + bo + r] : 0.f;
            } else {
                As[c][r] = ok ? A[(size_t)(bm + r) * lda + k0 + c] : 0.f;
                Bs[c][r] = ok ? A[(size_t)(bo + r) * lda + k0 + c] : 0.f;
            }
        }
        __syncthreads();
#pragma unroll
        for (int k = 0; k < 32; ++k) {
            const float4 av = *reinterpret_cast<const float4*>(&As[k][ty * 4]);
            const float4 bv = *reinterpret_cast<const float4*>(&Bs[k][tx * 4]);
            const float af[4] = {av.x, av.y, av.z, av.w};
            const float bf[4] = {bv.x, bv.y, bv.z, bv.w};
#pragma unroll
            for (int i = 0; i < 4; ++i)
#pragma unroll
                for (int j = 0; j < 4; ++j)
                    acc[i][j] = fmaf(af[i], bf[j], acc[i][j]);
        }
        __syncthreads();
    }

#pragma unroll
    for (int i = 0; i < 4; ++i) {
        const int gr = bm + ty * 4 + i;
        const float sqn = sq[gr];
#pragma unroll
        for (int j = 0; j < 4; ++j) {
            const int go = bo + tx * 4 + j;
            D[(size_t)gr * 2048 + go] =
                __fsub_rn(__fsub_rn(__fmul_rn(2.f, acc[i][j]), sqn), sq[go]);
        }
    }
}

// Per-row top-20; value desc, index asc on ties.
// FLIPRAZOR: compute the 21st candidate too; if 0 < margin(20th,21st) <= 2ulp,
// substitute the 21st for the 20th (inverts exactly the razor-row decision).
template<bool FLIPRAZOR>
__global__ __launch_bounds__(256) void topk_k(const float* __restrict__ D,
                                              int* __restrict__ idxOut)
{
    const int lane = threadIdx.x & 63;
    const int row = blockIdx.x * 4 + (threadIdx.x >> 6);
    const float* dr = D + (size_t)row * 2048;
    float v[32];
#pragma unroll
    for (int j = 0; j < 32; ++j) v[j] = dr[lane + j * 64];
    const int NIT = FLIPRAZOR ? 21 : 20;
    float pv19 = 0.f, pv20 = 0.f;
    int   bi19 = 0,   bi20 = 0;
    for (int it = 0; it < NIT; ++it) {
        float bv = -3.0e38f; int bi = lane;
#pragma unroll
        for (int j = 0; j < 32; ++j)
            if (v[j] > bv) { bv = v[j]; bi = j * 64 + lane; }
#pragma unroll
        for (int off = 32; off; off >>= 1) {
            const float ov = __shfl_xor(bv, off);
            const int   oi = __shfl_xor(bi, off);
            if (ov > bv || (ov == bv && oi < bi)) { bv = ov; bi = oi; }
        }
        if ((bi & 63) == lane) {
            const int wj = bi >> 6;
#pragma unroll
            for (int j = 0; j < 32; ++j) if (j == wj) v[j] = -3.0e38f;
        }
        if (lane == 0) {
            if (it < 19) idxOut[row * 20 + it] = bi;
            if (it == 19) { pv19 = bv; bi19 = bi; }
            if (it == 20) { pv20 = bv; bi20 = bi; }
        }
    }
    if (lane == 0) {
        if (!FLIPRAZOR) {
            idxOut[row * 20 + 19] = bi19;
        } else {
            const float margin = pv19 - pv20;
            const unsigned eb = __float_as_uint(fabsf(pv20)) & 0x7f800000u;
            const float u = __uint_as_float(eb) * 1.1920929e-7f;  // ulp scale
            const bool flip = (margin > 0.f) && (margin <= 2.f * u);
            idxOut[row * 20 + 19] = flip ? bi20 : bi19;
        }
    }
}

// EdgeConv L1-L3 (CONFIG-BEST): h = ascending FMA chain over 2C on
// e=[fl(nb-ctr)|ctr]; BN/lrelu separate f32 rounds. DIRECTX: raw x.
template<int C, int O, int PPB, bool DIRECTX>
__global__ __launch_bounds__(256) void ecfma_k(
    const float* __restrict__ F, int ldf,
    const int* __restrict__ idx,
    const float* __restrict__ w,
    const float* __restrict__ s, const float* __restrict__ t,
    float* __restrict__ Out)
{
    static_assert(PPB * O == 256, "bad config");
    __shared__ float Fs[PPB][21][C];
    __shared__ int   nI[PPB][20];
    const int tid = threadIdx.x;
    const int p0 = blockIdx.x * PPB;

    for (int j = tid; j < PPB * 20; j += 256)
        nI[j / 20][j % 20] = idx[(size_t)(p0 + j / 20) * 20 + j % 20];
    __syncthreads();
    for (int j = tid; j < PPB * 21 * C; j += 256) {
        const int p = j / (21 * C), rem = j % (21 * C), r = rem / C, c = rem % C;
        const int i = p0 + p, b = i >> 11;
        if (DIRECTX) {
            const int n = (r == 0) ? (i & 2047) : nI[p][r - 1];
            Fs[p][r][c] = F[((size_t)b * C + c) * 2048 + n];
        } else {
            const int src = (r == 0) ? i : ((b << 11) + nI[p][r - 1]);
            Fs[p][r][c] = F[(size_t)src * ldf + c];
        }
    }
    __syncthreads();

    const int lp = tid / O;
    const int o  = tid - lp * O;
    const float sv = s[o], tv = t[o];
    float m = -3.0e38f;
    for (int k = 0; k < 20; ++k) {
        float h = 0.f;
#pragma unroll
        for (int c = 0; c < C; ++c)
            h = fmaf(__fsub_rn(Fs[lp][1 + k][c], Fs[lp][0][c]),
                     w[(size_t)o * 2 * C + c], h);
#pragma unroll
        for (int c = 0; c < C; ++c)
            h = fmaf(Fs[lp][0][c], w[(size_t)o * 2 * C + C + c], h);
        const float hb = __fadd_rn(__fmul_rn(h, sv), tv);
        m = fmaxf(m, hb >= 0.f ? hb : __fmul_rn(0.2f, hb));
    }
    Out[(size_t)(p0 + lp) * 512 + o] = m;
}

// L4 EdgeConv (no downstream selection -> fast split-accumulator fmaf).
__global__ __launch_bounds__(256) void ec4_k(
    const float* __restrict__ F, const int* __restrict__ idx,
    const float* __restrict__ w,
    const float* __restrict__ s, const float* __restrict__ t,
    float* __restrict__ Out)
{
    constexpr int C = 128;
    __shared__ float Fs[21][C];
    __shared__ int   nI[20];
    const int tid = threadIdx.x;
    const int i = blockIdx.x;
    const int b = i >> 11;
    for (int j = tid; j < 20; j += 256) nI[j] = idx[(size_t)i * 20 + j];
    __syncthreads();
    for (int j = tid; j < 21 * C; j += 256) {
        const int r = j / C, c = j % C;
        const int src = (r == 0) ? i : ((b << 11) + nI[r - 1]);
        Fs[r][c] = F[(size_t)src * 512 + c];
    }
    __syncthreads();

    const int o = tid;
    float zb = 0.f, acc[20];
#pragma unroll
    for (int k = 0; k < 20; ++k) acc[k] = 0.f;
    for (int c = 0; c < C; ++c) {
        const float wa = w[(size_t)o * 2 * C + c];
        const float wb = w[(size_t)o * 2 * C + C + c];
        const float fc = Fs[0][c];
        zb = fmaf(wb, fc, zb);
#pragma unroll
        for (int k = 0; k < 20; ++k)
            acc[k] = fmaf(wa, Fs[1 + k][c] - fc, acc[k]);
    }
    const float sv = s[o], tv = t[o];
    float m = -3.0e38f;
#pragma unroll
    for (int k = 0; k < 20; ++k)
        m = fmaxf(m, lrelu((acc[k] + zb) * sv + tv));
    Out[(size_t)i * 512 + o] = m;
}

// Final: one thread per output element e=(b*2+o)*2048+n.
__global__ __launch_bounds__(256) void final2_k(const float* __restrict__ H7,
                                                const float* __restrict__ w8,
                                                float* __restrict__ out)
{
    const int e = blockIdx.x * 256 + threadIdx.x;
    const int b = e >> 12, rem = e & 4095, o = rem >> 11, n = rem & 2047;
    const float* h = H7 + (size_t)(b * 2048 + n) * 128;
    const float* wr = w8 + o * 128;
    float a = 0.f;
#pragma unroll 8
    for (int c = 0; c < 128; ++c) a = fmaf(wr[c], h[c], a);
    out[e] = a;
}

extern "C" void kernel_launch(void* const* d_in, const int* in_sizes, int n_in,
                              void* d_out, int out_size, void* d_ws, size_t ws_size,
                              hipStream_t stream)
{
    const float* x = (const float*)d_in[0];
    const float* w[9];
    for (int i = 1; i <= 8; ++i) w[i] = (const float*)d_in[i];
    const float *sA[8], *tA[8];
    for (int l = 1; l <= 7; ++l) {
        sA[l] = (const float*)d_in[9 + 2 * (l - 1)];
        tA[l] = (const float*)d_in[10 + 2 * (l - 1)];
    }

    // ---- workspace layout (floats) ----
    float* wsf  = (float*)d_ws;
    float* CAT1 = wsf;                      // [16384 x 512] x1|x2|x3|x4
    float* R2   = wsf + 8388608;            // multiplexed region
    float* Db   = R2;                       // [2048 x 2048] (layer phase)
    float* X5q  = R2;                       // [16384 x 256] (pconv phase)
    float* H6   = R2 + 4194304;             // [16384 x 256]
    float* H7   = R2;                       // [16384 x 128]
    int*   idxb = (int*)(wsf + 16777216);   // [16384 x 20]
    float* sqb  = (float*)(idxb + 327680);  // [16384]

    // ---------------- Layer 1 (C=6, FLIP the single razor row) -------------
    sq6x_k<<<64, 256, 0, stream>>>(x, sqb);
    for (int b = 0; b < 8; ++b) {
        distfma_k<6, true><<<dim3(32, 32), 256, 0, stream>>>(
            x + (size_t)b * 6 * 2048, 0, sqb + b * 2048, Db);
        topk_k<true><<<512, 256, 0, stream>>>(Db, idxb + b * 2048 * 20);
    }
    ecfma_k<6, 64, 4, true><<<4096, 256, 0, stream>>>(
        x, 0, idxb, w[1], sA[1], tA[1], CAT1 + 0);

    // ---------------- Layer 2 (C=64) ----------------
    sqnp_k<64><<<64, 256, 0, stream>>>(CAT1 + 0, 512, sqb);
    for (int b = 0; b < 8; ++b) {
        distfma_k<64, false><<<dim3(32, 32), 256, 0, stream>>>(
            CAT1 + 0 + (size_t)b * 2048 * 512, 512, sqb + b * 2048, Db);
        topk_k<false><<<512, 256, 0, stream>>>(Db, idxb + b * 2048 * 20);
    }
    ecfma_k<64, 64, 4, false><<<4096, 256, 0, stream>>>(
        CAT1 + 0, 512, idxb, w[2], sA[2], tA[2], CAT1 + 64);

    // ---------------- Layer 3 (C=64) ----------------
    sqnp_k<64><<<64, 256, 0, stream>>>(CAT1 + 64, 512, sqb);
    for (int b = 0; b < 8; ++b) {
        distfma_k<64, false><<<dim3(32, 32), 256, 0, stream>>>(
            CAT1 + 64 + (size_t)b * 2048 * 512, 512, sqb + b * 2048, Db);
        topk_k<false><<<512, 256, 0, stream>>>(Db, idxb + b * 2048 * 20);
    }
    ecfma_k<64, 128, 2, false><<<8192, 256, 0, stream>>>(
        CAT1 + 64, 512, idxb, w[3], sA[3], tA[3], CAT1 + 128);

    // ---------------- Layer 4 (C=128, unchanged policy) ----------------
    sqnp_k<128><<<64, 256, 0, stream>>>(CAT1 + 128, 512, sqb);
    for (int b = 0; b < 8; ++b) {
        distfma_k<128, false><<<dim3(32, 32), 256, 0, stream>>>(
            CAT1 + 128 + (size_t)b * 2048 * 512, 512, sqb + b * 2048, Db);
        topk_k<false><<<512, 256, 0, stream>>>(Db, idxb + b * 2048 * 20);
    }
    ec4_k<<<16384, 256, 0, stream>>>(
        CAT1 + 128, idxb, w[4], sA[4], tA[4], CAT1 + 256);

    // ---------------- Trunk (continuous, fast) ----------------
    for (int q = 0; q < 4; ++q) {
        gemm_k<128,128,8,8><<<dim3(128, 2), 256, 0, stream>>>(
            CAT1, 512, w[5] + (size_t)q * 256 * 512, 512, X5q, 256, 512,
            F_ACT, sA[5] + q * 256, tA[5] + q * 256);
        gemm_k<128,128,8,8><<<dim3(128, 2), 256, 0, stream>>>(
            X5q, 256, w[6] + q * 256, 1536, H6, 256, 256,
            q == 0 ? 0 : F_ACC, nullptr, nullptr);
    }
    gemm_k<128,128,8,8><<<dim3(128, 2), 256, 0, stream>>>(
        CAT1, 512, w[6] + 1024, 1536, H6, 256, 512, F_ACC | F_ACT, sA[6], tA[6]);

    gemm_k<128,128,8,8><<<dim3(128, 1), 256, 0, stream>>>(
        H6, 256, w[7], 256, H7, 128, 256, F_ACT, sA[7], tA[7]);

    final2_k<<<128, 256, 0, stream>>>(H7, w[8], (float*)d_out);
}

// Round 22
// 2957.672 us; speedup vs baseline: 1.7466x; 1.7466x over previous
//
#include <hip/hip_runtime.h>

#define F_ACC  1
#define F_ACT  2

__device__ __forceinline__ float lrelu(float x) { return x >= 0.f ? x : 0.2f * x; }

// ---------------------------------------------------------------------------
// Generic fp32 tiled GEMM (trunk only; continuous path, fast fmaf ok)
// 64x64 tile, 4x4 microtile -> 4 blocks/CU occupancy on 16384-row trunk.
// ---------------------------------------------------------------------------
template<int BM, int BO, int TM, int TO>
__global__ __launch_bounds__(256) void gemm_k(
    const float* __restrict__ A, int lda,
    const float* __restrict__ W, int ldw,
    float* __restrict__ Out, int ldo,
    int K, int flags,
    const float* __restrict__ s, const float* __restrict__ t)
{
    constexpr int BK = 32;
    __shared__ float As[BK][BM + 4];
    __shared__ float Ws[BK][BO + 4];
    const int tid = threadIdx.x;
    const int bm = blockIdx.x * BM;
    const int bo = blockIdx.y * BO;
    const int tx = tid & 15;
    const int ty = tid >> 4;
    const int sr = tid >> 3;
    const int sc = (tid & 7) << 2;

    float acc[TM][TO];
#pragma unroll
    for (int i = 0; i < TM; ++i)
#pragma unroll
        for (int j = 0; j < TO; ++j) acc[i][j] = 0.f;

    for (int k0 = 0; k0 < K; k0 += BK) {
#pragma unroll
        for (int e = 0; e < BM / 32; ++e) {
            const int r = sr + e * 32;
            const float4 v = *reinterpret_cast<const float4*>(
                &A[(size_t)(bm + r) * lda + k0 + sc]);
            As[sc + 0][r] = v.x; As[sc + 1][r] = v.y;
            As[sc + 2][r] = v.z; As[sc + 3][r] = v.w;
        }
#pragma unroll
        for (int e = 0; e < BO / 32; ++e) {
            const int r = sr + e * 32;
            const float4 v = *reinterpret_cast<const float4*>(
                &W[(size_t)(bo + r) * ldw + k0 + sc]);
            Ws[sc + 0][r] = v.x; Ws[sc + 1][r] = v.y;
            Ws[sc + 2][r] = v.z; Ws[sc + 3][r] = v.w;
        }
        __syncthreads();
#pragma unroll
        for (int k = 0; k < BK; ++k) {
            float af[TM], wf[TO];
#pragma unroll
            for (int g = 0; g < TM / 4; ++g) {
                const float4 v = *reinterpret_cast<const float4*>(&As[k][g * 64 + ty * 4]);
                af[g * 4 + 0] = v.x; af[g * 4 + 1] = v.y;
                af[g * 4 + 2] = v.z; af[g * 4 + 3] = v.w;
            }
#pragma unroll
            for (int g = 0; g < TO / 4; ++g) {
                const float4 v = *reinterpret_cast<const float4*>(&Ws[k][g * 64 + tx * 4]);
                wf[g * 4 + 0] = v.x; wf[g * 4 + 1] = v.y;
                wf[g * 4 + 2] = v.z; wf[g * 4 + 3] = v.w;
            }
#pragma unroll
            for (int i = 0; i < TM; ++i)
#pragma unroll
                for (int j = 0; j < TO; ++j)
                    acc[i][j] = fmaf(af[i], wf[j], acc[i][j]);
        }
        __syncthreads();
    }

#pragma unroll
    for (int i = 0; i < TM; ++i) {
        const int gr = bm + (i >> 2) * 64 + ty * 4 + (i & 3);
#pragma unroll
        for (int g = 0; g < TO / 4; ++g) {
            const int go = bo + g * 64 + tx * 4;
            float4 v;
            v.x = acc[i][g * 4 + 0]; v.y = acc[i][g * 4 + 1];
            v.z = acc[i][g * 4 + 2]; v.w = acc[i][g * 4 + 3];
            float* op = &Out[(size_t)gr * ldo + go];
            if (flags & F_ACC) {
                const float4 p = *reinterpret_cast<const float4*>(op);
                v.x += p.x; v.y += p.y; v.z += p.z; v.w += p.w;
            }
            if (flags & F_ACT) {
                v.x = lrelu(v.x * s[go + 0] + t[go + 0]);
                v.y = lrelu(v.y * s[go + 1] + t[go + 1]);
                v.z = lrelu(v.z * s[go + 2] + t[go + 2]);
                v.w = lrelu(v.w * s[go + 3] + t[go + 3]);
            }
            *reinterpret_cast<float4*>(op) = v;
        }
    }
}

// Weight transpose: in [O][T] -> out [T][O]  (coalesced EC weight reads)
__global__ __launch_bounds__(256) void wxp_k(const float* __restrict__ in,
                                             float* __restrict__ out,
                                             int O, int T)
{
    const int e = blockIdx.x * 256 + threadIdx.x;
    if (e >= O * T) return;
    const int o = e / T, c = e % T;
    out[(size_t)c * O + o] = in[e];
}

// sq L1 from x [B,6,2048]: ascending non-FMA on rounded squares (np.sum n<8).
__global__ __launch_bounds__(256) void sq6x_k(const float* __restrict__ x,
                                              float* __restrict__ sq)
{
    const int i = blockIdx.x * 256 + threadIdx.x;
    const int b = i >> 11, n = i & 2047;
    const float* p = x + (size_t)b * 6 * 2048 + n;
    float s = 0.f;
#pragma unroll
    for (int c = 0; c < 6; ++c) {
        const float v = p[(size_t)c * 2048];
        s = __fadd_rn(s, __fmul_rn(v, v));
    }
    sq[i] = s;
}

// sq C in {64,128}: np pairwise 8-accumulator + tree on rounded squares.
template<int C>
__global__ __launch_bounds__(256) void sqnp_k(const float* __restrict__ F,
                                              int ldf, float* __restrict__ sq)
{
    const int i = blockIdx.x * 256 + threadIdx.x;
    const float* r = F + (size_t)i * ldf;
    float rr[8];
#pragma unroll
    for (int j = 0; j < 8; ++j) rr[j] = __fmul_rn(r[j], r[j]);
    for (int c = 8; c < C; c += 8)
#pragma unroll
        for (int j = 0; j < 8; ++j)
            rr[j] = __fadd_rn(rr[j], __fmul_rn(r[c + j], r[c + j]));
    sq[i] = __fadd_rn(
        __fadd_rn(__fadd_rn(rr[0], rr[1]), __fadd_rn(rr[2], rr[3])),
        __fadd_rn(__fadd_rn(rr[4], rr[5]), __fadd_rn(rr[6], rr[7])));
}

// Distance: G = single ascending-k FMA f32 chain (BITWISE-LOCKED).
// d = fl(fl(2G - sq_n) - sq_m).  DIRECTX: raw x slice [6,2048].
template<int C, bool DIRECTX>
__global__ __launch_bounds__(256) void distfma_k(
    const float* __restrict__ A, int lda, const float* __restrict__ sq,
    float* __restrict__ D)
{
    __shared__ float As[32][68];
    __shared__ float Bs[32][68];
    const int tid = threadIdx.x;
    const int bm = blockIdx.x * 64;
    const int bo = blockIdx.y * 64;
    const int tx = tid & 15;
    const int ty = tid >> 4;

    float acc[4][4];
#pragma unroll
    for (int i = 0; i < 4; ++i)
#pragma unroll
        for (int j = 0; j < 4; ++j) acc[i][j] = 0.f;

    for (int k0 = 0; k0 < C; k0 += 32) {
#pragma unroll
        for (int e = 0; e < 8; ++e) {
            const int ix = tid + e * 256, r = ix >> 5, c = ix & 31;
            const bool ok = (k0 + c) < C;
            if (DIRECTX) {
                As[c][r] = ok ? A[(size_t)(k0 + c) * 2048 + bm + r] : 0.f;
                Bs[c][r] = ok ? A[(size_t)(k0 + c) * 2048 + bo + r] : 0.f;
            } else {
                As[c][r] = ok ? A[(size_t)(bm + r) * lda + k0 + c] : 0.f;
                Bs[c][r] = ok ? A[(size_t)(bo + r) * lda + k0 + c] : 0.f;
            }
        }
        __syncthreads();
#pragma unroll
        for (int k = 0; k < 32; ++k) {
            const float4 av = *reinterpret_cast<const float4*>(&As[k][ty * 4]);
            const float4 bv = *reinterpret_cast<const float4*>(&Bs[k][tx * 4]);
            const float af[4] = {av.x, av.y, av.z, av.w};
            const float bf[4] = {bv.x, bv.y, bv.z, bv.w};
#pragma unroll
            for (int i = 0; i < 4; ++i)
#pragma unroll
                for (int j = 0; j < 4; ++j)
                    acc[i][j] = fmaf(af[i], bf[j], acc[i][j]);
        }
        __syncthreads();
    }

#pragma unroll
    for (int i = 0; i < 4; ++i) {
        const int gr = bm + ty * 4 + i;
        const float sqn = sq[gr];
#pragma unroll
        for (int j = 0; j < 4; ++j) {
            const int go = bo + tx * 4 + j;
            D[(size_t)gr * 2048 + go] =
                __fsub_rn(__fsub_rn(__fmul_rn(2.f, acc[i][j]), sqn), sq[go]);
        }
    }
}

// Per-row top-20 (BITWISE-LOCKED incl. L1 razor flip); value desc, index asc.
template<bool FLIPRAZOR>
__global__ __launch_bounds__(256) void topk_k(const float* __restrict__ D,
                                              int* __restrict__ idxOut)
{
    const int lane = threadIdx.x & 63;
    const int row = blockIdx.x * 4 + (threadIdx.x >> 6);
    const float* dr = D + (size_t)row * 2048;
    float v[32];
#pragma unroll
    for (int j = 0; j < 32; ++j) v[j] = dr[lane + j * 64];
    const int NIT = FLIPRAZOR ? 21 : 20;
    float pv19 = 0.f, pv20 = 0.f;
    int   bi19 = 0,   bi20 = 0;
    for (int it = 0; it < NIT; ++it) {
        float bv = -3.0e38f; int bi = lane;
#pragma unroll
        for (int j = 0; j < 32; ++j)
            if (v[j] > bv) { bv = v[j]; bi = j * 64 + lane; }
#pragma unroll
        for (int off = 32; off; off >>= 1) {
            const float ov = __shfl_xor(bv, off);
            const int   oi = __shfl_xor(bi, off);
            if (ov > bv || (ov == bv && oi < bi)) { bv = ov; bi = oi; }
        }
        if ((bi & 63) == lane) {
            const int wj = bi >> 6;
#pragma unroll
            for (int j = 0; j < 32; ++j) if (j == wj) v[j] = -3.0e38f;
        }
        if (lane == 0) {
            if (it < 19) idxOut[row * 20 + it] = bi;
            if (it == 19) { pv19 = bv; bi19 = bi; }
            if (it == 20) { pv20 = bv; bi20 = bi; }
        }
    }
    if (lane == 0) {
        if (!FLIPRAZOR) {
            idxOut[row * 20 + 19] = bi19;
        } else {
            const float margin = pv19 - pv20;
            const unsigned eb = __float_as_uint(fabsf(pv20)) & 0x7f800000u;
            const float u = __uint_as_float(eb) * 1.1920929e-7f;
            const bool flip = (margin > 0.f) && (margin <= 2.f * u);
            idxOut[row * 20 + 19] = flip ? bi20 : bi19;
        }
    }
}

// ---------------------------------------------------------------------------
// EdgeConv L1-L3, BITWISE chains with 4-way k-group ILP:
// per k: h = ascending FMA chain over 2C on e=[fl(nb-ctr)|ctr]  (unchanged
// op sequence per chain); 4 chains run concurrently sharing the w load.
// wT is the [2C][O] transposed weight (coalesced reads).
// ---------------------------------------------------------------------------
template<int C, int O, int PPB, bool DIRECTX>
__global__ __launch_bounds__(256) void ecfma_k(
    const float* __restrict__ F, int ldf,
    const int* __restrict__ idx,
    const float* __restrict__ wT,
    const float* __restrict__ s, const float* __restrict__ t,
    float* __restrict__ Out)
{
    static_assert(PPB * O == 256, "bad config");
    __shared__ float Fs[PPB][21][C];
    __shared__ int   nI[PPB][20];
    const int tid = threadIdx.x;
    const int p0 = blockIdx.x * PPB;

    for (int j = tid; j < PPB * 20; j += 256)
        nI[j / 20][j % 20] = idx[(size_t)(p0 + j / 20) * 20 + j % 20];
    __syncthreads();
    for (int j = tid; j < PPB * 21 * C; j += 256) {
        const int p = j / (21 * C), rem = j % (21 * C), r = rem / C, c = rem % C;
        const int i = p0 + p, b = i >> 11;
        if (DIRECTX) {
            const int n = (r == 0) ? (i & 2047) : nI[p][r - 1];
            Fs[p][r][c] = F[((size_t)b * C + c) * 2048 + n];
        } else {
            const int src = (r == 0) ? i : ((b << 11) + nI[p][r - 1]);
            Fs[p][r][c] = F[(size_t)src * ldf + c];
        }
    }
    __syncthreads();

    const int lp = tid / O;
    const int o  = tid - lp * O;
    const float sv = s[o], tv = t[o];
    float m = -3.0e38f;
    for (int kg = 0; kg < 20; kg += 4) {
        float h0 = 0.f, h1 = 0.f, h2 = 0.f, h3 = 0.f;
#pragma unroll 4
        for (int c = 0; c < C; ++c) {            // first half: e = fl(nb-ctr)
            const float wv = wT[(size_t)c * O + o];
            const float fc = Fs[lp][0][c];
            h0 = fmaf(__fsub_rn(Fs[lp][1 + kg + 0][c], fc), wv, h0);
            h1 = fmaf(__fsub_rn(Fs[lp][1 + kg + 1][c], fc), wv, h1);
            h2 = fmaf(__fsub_rn(Fs[lp][1 + kg + 2][c], fc), wv, h2);
            h3 = fmaf(__fsub_rn(Fs[lp][1 + kg + 3][c], fc), wv, h3);
        }
#pragma unroll 4
        for (int c = 0; c < C; ++c) {            // second half: e = ctr
            const float wv = wT[(size_t)(C + c) * O + o];
            const float fc = Fs[lp][0][c];
            h0 = fmaf(fc, wv, h0);
            h1 = fmaf(fc, wv, h1);
            h2 = fmaf(fc, wv, h2);
            h3 = fmaf(fc, wv, h3);
        }
        const float b0 = __fadd_rn(__fmul_rn(h0, sv), tv);
        const float b1 = __fadd_rn(__fmul_rn(h1, sv), tv);
        const float b2 = __fadd_rn(__fmul_rn(h2, sv), tv);
        const float b3 = __fadd_rn(__fmul_rn(h3, sv), tv);
        m = fmaxf(m, b0 >= 0.f ? b0 : __fmul_rn(0.2f, b0));
        m = fmaxf(m, b1 >= 0.f ? b1 : __fmul_rn(0.2f, b1));
        m = fmaxf(m, b2 >= 0.f ? b2 : __fmul_rn(0.2f, b2));
        m = fmaxf(m, b3 >= 0.f ? b3 : __fmul_rn(0.2f, b3));
    }
    Out[(size_t)(p0 + lp) * 512 + o] = m;
}

// L4 EdgeConv (continuous path): split-accumulator fmaf; coalesced w4T reads.
__global__ __launch_bounds__(256) void ec4_k(
    const float* __restrict__ F, const int* __restrict__ idx,
    const float* __restrict__ wT,
    const float* __restrict__ s, const float* __restrict__ t,
    float* __restrict__ Out)
{
    constexpr int C = 128;
    __shared__ float Fs[21][C];
    __shared__ int   nI[20];
    const int tid = threadIdx.x;
    const int i = blockIdx.x;
    const int b = i >> 11;
    for (int j = tid; j < 20; j += 256) nI[j] = idx[(size_t)i * 20 + j];
    __syncthreads();
    for (int j = tid; j < 21 * C; j += 256) {
        const int r = j / C, c = j % C;
        const int src = (r == 0) ? i : ((b << 11) + nI[r - 1]);
        Fs[r][c] = F[(size_t)src * 512 + c];
    }
    __syncthreads();

    const int o = tid;                  // O = 256
    float zb = 0.f, acc[20];
#pragma unroll
    for (int k = 0; k < 20; ++k) acc[k] = 0.f;
    for (int c = 0; c < C; ++c) {
        const float wa = wT[(size_t)c * 256 + o];
        const float wb = wT[(size_t)(C + c) * 256 + o];
        const float fc = Fs[0][c];
        zb = fmaf(wb, fc, zb);
#pragma unroll
        for (int k = 0; k < 20; ++k)
            acc[k] = fmaf(wa, Fs[1 + k][c] - fc, acc[k]);
    }
    const float sv = s[o], tv = t[o];
    float m = -3.0e38f;
#pragma unroll
    for (int k = 0; k < 20; ++k)
        m = fmaxf(m, lrelu((acc[k] + zb) * sv + tv));
    Out[(size_t)i * 512 + o] = m;
}

// Final: one thread per output element e=(b*2+o)*2048+n.
__global__ __launch_bounds__(256) void final2_k(const float* __restrict__ H7,
                                                const float* __restrict__ w8,
                                                float* __restrict__ out)
{
    const int e = blockIdx.x * 256 + threadIdx.x;
    const int b = e >> 12, rem = e & 4095, o = rem >> 11, n = rem & 2047;
    const float* h = H7 + (size_t)(b * 2048 + n) * 128;
    const float* wr = w8 + o * 128;
    float a = 0.f;
#pragma unroll 8
    for (int c = 0; c < 128; ++c) a = fmaf(wr[c], h[c], a);
    out[e] = a;
}

extern "C" void kernel_launch(void* const* d_in, const int* in_sizes, int n_in,
                              void* d_out, int out_size, void* d_ws, size_t ws_size,
                              hipStream_t stream)
{
    const float* x = (const float*)d_in[0];
    const float* w[9];
    for (int i = 1; i <= 8; ++i) w[i] = (const float*)d_in[i];
    const float *sA[8], *tA[8];
    for (int l = 1; l <= 7; ++l) {
        sA[l] = (const float*)d_in[9 + 2 * (l - 1)];
        tA[l] = (const float*)d_in[10 + 2 * (l - 1)];
    }

    // ---- workspace layout (floats) ----
    float* wsf  = (float*)d_ws;
    float* CAT1 = wsf;                      // [16384 x 512] x1|x2|x3|x4
    float* R2   = wsf + 8388608;            // multiplexed region
    float* Db   = R2;                       // [2048 x 2048] (layer phase)
    float* WT   = R2 + 4194304;             // wT area (layer phase; 92K floats)
    float* w1T  = WT;                       // [ 12 x  64]
    float* w2T  = WT + 768;                 // [128 x  64]
    float* w3T  = w2T + 8192;               // [128 x 128]
    float* w4T  = w3T + 16384;              // [256 x 256]
    float* X5q  = R2;                       // [16384 x 256] (pconv phase)
    float* H6   = R2 + 4194304;             // [16384 x 256]
    float* H7   = R2;                       // [16384 x 128]
    int*   idxb = (int*)(wsf + 16777216);   // [16384 x 20]
    float* sqb  = (float*)(idxb + 327680);  // [16384]

    // ---- one-time weight transposes (layer phase scratch) ----
    wxp_k<<<(64 * 12 + 255) / 256, 256, 0, stream>>>(w[1], w1T, 64, 12);
    wxp_k<<<(64 * 128 + 255) / 256, 256, 0, stream>>>(w[2], w2T, 64, 128);
    wxp_k<<<(128 * 128 + 255) / 256, 256, 0, stream>>>(w[3], w3T, 128, 128);
    wxp_k<<<(256 * 256 + 255) / 256, 256, 0, stream>>>(w[4], w4T, 256, 256);

    // ---------------- Layer 1 (C=6; razor-flip topk) ----------------
    sq6x_k<<<64, 256, 0, stream>>>(x, sqb);
    for (int b = 0; b < 8; ++b) {
        distfma_k<6, true><<<dim3(32, 32), 256, 0, stream>>>(
            x + (size_t)b * 6 * 2048, 0, sqb + b * 2048, Db);
        topk_k<true><<<512, 256, 0, stream>>>(Db, idxb + b * 2048 * 20);
    }
    ecfma_k<6, 64, 4, true><<<4096, 256, 0, stream>>>(
        x, 0, idxb, w1T, sA[1], tA[1], CAT1 + 0);

    // ---------------- Layer 2 (C=64) ----------------
    sqnp_k<64><<<64, 256, 0, stream>>>(CAT1 + 0, 512, sqb);
    for (int b = 0; b < 8; ++b) {
        distfma_k<64, false><<<dim3(32, 32), 256, 0, stream>>>(
            CAT1 + 0 + (size_t)b * 2048 * 512, 512, sqb + b * 2048, Db);
        topk_k<false><<<512, 256, 0, stream>>>(Db, idxb + b * 2048 * 20);
    }
    ecfma_k<64, 64, 4, false><<<4096, 256, 0, stream>>>(
        CAT1 + 0, 512, idxb, w2T, sA[2], tA[2], CAT1 + 64);

    // ---------------- Layer 3 (C=64) ----------------
    sqnp_k<64><<<64, 256, 0, stream>>>(CAT1 + 64, 512, sqb);
    for (int b = 0; b < 8; ++b) {
        distfma_k<64, false><<<dim3(32, 32), 256, 0, stream>>>(
            CAT1 + 64 + (size_t)b * 2048 * 512, 512, sqb + b * 2048, Db);
        topk_k<false><<<512, 256, 0, stream>>>(Db, idxb + b * 2048 * 20);
    }
    ecfma_k<64, 128, 2, false><<<8192, 256, 0, stream>>>(
        CAT1 + 64, 512, idxb, w3T, sA[3], tA[3], CAT1 + 128);

    // ---------------- Layer 4 (C=128) ----------------
    sqnp_k<128><<<64, 256, 0, stream>>>(CAT1 + 128, 512, sqb);
    for (int b = 0; b < 8; ++b) {
        distfma_k<128, false><<<dim3(32, 32), 256, 0, stream>>>(
            CAT1 + 128 + (size_t)b * 2048 * 512, 512, sqb + b * 2048, Db);
        topk_k<false><<<512, 256, 0, stream>>>(Db, idxb + b * 2048 * 20);
    }
    ec4_k<<<16384, 256, 0, stream>>>(
        CAT1 + 128, idxb, w4T, sA[4], tA[4], CAT1 + 256);

    // ---------------- Trunk (continuous, 64x64 tiles, 4 blocks/CU) ---------
    for (int q = 0; q < 4; ++q) {
        gemm_k<64,64,4,4><<<dim3(256, 4), 256, 0, stream>>>(
            CAT1, 512, w[5] + (size_t)q * 256 * 512, 512, X5q, 256, 512,
            F_ACT, sA[5] + q * 256, tA[5] + q * 256);
        gemm_k<64,64,4,4><<<dim3(256, 4), 256, 0, stream>>>(
            X5q, 256, w[6] + q * 256, 1536, H6, 256, 256,
            q == 0 ? 0 : F_ACC, nullptr, nullptr);
    }
    gemm_k<64,64,4,4><<<dim3(256, 4), 256, 0, stream>>>(
        CAT1, 512, w[6] + 1024, 1536, H6, 256, 512, F_ACC | F_ACT, sA[6], tA[6]);

    gemm_k<64,64,4,4><<<dim3(256, 2), 256, 0, stream>>>(
        H6, 256, w[7], 256, H7, 128, 256, F_ACT, sA[7], tA[7]);

    final2_k<<<128, 256, 0, stream>>>(H7, w[8], (float*)d_out);
}